// Round 21
// baseline (260.006 us; speedup 1.0000x reference)
//
#include <hip/hip_runtime.h>
#include <hip/hip_bf16.h>
#include <math.h>

// MLA forward: B=2 T=2048 C=2048 H=16 NOPE=128 ROPE=64 VD=128 LORA=512 QK=192

typedef short bf16x8 __attribute__((ext_vector_type(8)));
typedef short short4v __attribute__((ext_vector_type(4)));
typedef float f32x4 __attribute__((ext_vector_type(4)));
typedef float f32x16 __attribute__((ext_vector_type(16)));

#define MFMA16(a, b, c) __builtin_amdgcn_mfma_f32_16x16x32_bf16(a, b, c, 0, 0, 0)
#define MFMA32(a, b, c) __builtin_amdgcn_mfma_f32_32x32x16_bf16(a, b, c, 0, 0, 0)

__device__ __forceinline__ short f2bf(float f) {
  union { float f; unsigned u; } v; v.f = f;
  unsigned r = v.u + 0x7fffu + ((v.u >> 16) & 1u);
  return (short)(r >> 16);
}
__device__ __forceinline__ float bf2f(short s) {
  union { unsigned u; float f; } v;
  v.u = ((unsigned)(unsigned short)s) << 16;
  return v.f;
}
__device__ __forceinline__ unsigned cvtpk(float a, float b) {
  unsigned r;
  asm("v_cvt_pk_bf16_f32 %0, %1, %2" : "=v"(r) : "v"(a), "v"(b));
  return r;
}
__device__ __forceinline__ void gl16(const void* g, void* l) {
  __builtin_amdgcn_global_load_lds(
      (const __attribute__((address_space(1))) unsigned int*)g,
      (__attribute__((address_space(3))) unsigned int*)l, 16, 0, 0);
}
#define CFENCE() asm volatile("" ::: "memory")
#define HWBAR()  do { CFENCE(); __builtin_amdgcn_s_barrier(); CFENCE(); } while (0)

// ---------------- merged x-cvt + weight transpose+cvt: 5 jobs in one launch ----------------
// kv_norm_w folded into wdkv rows (Wdkv job): rmsnorm becomes a pure row-scale.
__global__ __launch_bounds__(256) void wcvt2_k(const float* __restrict__ x,
                                               const float* __restrict__ Wq,
                                               const float* __restrict__ Wckv,
                                               const float* __restrict__ Wdkv,
                                               const float* __restrict__ Wproj,
                                               const float* __restrict__ kvw,
                                               short* __restrict__ x_bf,
                                               short* __restrict__ wqc,
                                               short* __restrict__ wdkv,
                                               short* __restrict__ wproj) {
  __shared__ float tile[32][33];
  int id = blockIdx.x;
  if (id < 4096) {
    int i = (id * 256 + threadIdx.x) * 8;
    float4 a = *(const float4*)(x + i);
    float4 b = *(const float4*)(x + i + 4);
    bf16x8 o;
    o[0] = f2bf(a.x); o[1] = f2bf(a.y); o[2] = f2bf(a.z); o[3] = f2bf(a.w);
    o[4] = f2bf(b.x); o[5] = f2bf(b.y); o[6] = f2bf(b.z); o[7] = f2bf(b.w);
    *(bf16x8*)(x_bf + i) = o;
    return;
  }
  id -= 4096;
  const float* W; short* out; int K, N, gx, row_off, idx, job;
  if (id < 6144)      { idx = id;        W = Wq;    out = wqc;   K = 2048; N = 3072; gx = 64; row_off = 0;    job = 0; }
  else if (id < 7680) { idx = id - 6144; W = Wckv;  out = wqc;   K = 2048; N = 576;  gx = 64; row_off = 3072; job = 1; }
  else if (id < 9728) { idx = id - 7680; W = Wdkv;  out = wdkv;  K = 512;  N = 4096; gx = 16; row_off = 0;    job = 2; }
  else                { idx = id - 9728; W = Wproj; out = wproj; K = 2048; N = 2048; gx = 64; row_off = 0;    job = 3; }
  int k0 = (idx % gx) * 32, n0 = (idx / gx) * 32;
  int tx = threadIdx.x & 31, ty = threadIdx.x >> 5;
#pragma unroll
  for (int j = 0; j < 4; j++) {
    int k = k0 + ty + j * 8, n = n0 + tx;
    tile[ty + j * 8][tx] = (n < N) ? W[(size_t)k * N + n] : 0.f;
  }
  __syncthreads();
  float wk = (job == 2) ? kvw[k0 + tx] : 1.f;  // fold kv_norm_w (row index k = k0+tx)
#pragma unroll
  for (int j = 0; j < 4; j++) {
    int n = n0 + ty + j * 8;
    out[(size_t)(row_off + n) * K + k0 + tx] = f2bf(tile[tx][ty + j * 8] * wk);
  }
}

// ---------------- GEMM: triple-buffer counted-vmcnt phase-split (R16/R18/R20-proven loop) ----------------
// MODE 0: bf16 out. MODE 1: f32 out. MODE 2: kv scatter x rs[m] row-scale.
// MODE 3: GEMM1 fused scatter (q_all scaled / qrs / kvraw / krs).
template <int MODE, int BM, int BN, int SGL>
__global__ __launch_bounds__(512, 2) void gemm8_k(const short* __restrict__ A,
                                                  const short* __restrict__ Bt,
                                                  void* __restrict__ C1,
                                                  void* __restrict__ C2,
                                                  void* __restrict__ C3,
                                                  void* __restrict__ C4,
                                                  const float* __restrict__ rs,
                                                  int M, int N, int K, int nbx) {
  constexpr int FM = BM / 32;
  constexpr int FN = BN / 64;
  constexpr int XCH = (BM * 4) / 512;
  constexpr int YCH = (BN * 4) / 512;
  __shared__ short lX[3][BM * 32];
  __shared__ short lY[3][BN * 32];

  const int nwg = gridDim.x;
  const int cpx = nwg >> 3;
  const int swz = (blockIdx.x & 7) * cpx + (blockIdx.x >> 3);
  const int bx = swz % nbx, by = swz / nbx;
  const int m0 = bx * BM, n0 = by * BN;
  const int tid = threadIdx.x, lane = tid & 63, wave = tid >> 6;
  const int wm = wave >> 2, wn = wave & 3;
  const int l15 = lane & 15, l4 = lane >> 4;
  const int nt = K >> 5;

  auto stage = [&](int t) {
    int kk = t << 5;
    short* bX = &lX[t % 3][0];
    short* bY = &lY[t % 3][0];
#pragma unroll
    for (int c = 0; c < XCH; c++) {
      int idx = c * 512 + tid;
      int row = idx >> 2, seg = idx & 3;
      gl16(A + (size_t)(m0 + row) * K + kk + ((seg ^ ((row >> 1) & 3)) << 3),
           bX + idx * 8);
    }
#pragma unroll
    for (int c = 0; c < YCH; c++) {
      int idx = c * 512 + tid;
      int row = idx >> 2, seg = idx & 3;
      gl16(Bt + (size_t)(n0 + row) * K + kk + ((seg ^ ((row >> 1) & 3)) << 3),
           bY + idx * 8);
    }
  };

  f32x4 zero = {0.f, 0.f, 0.f, 0.f};
  f32x4 acc[FM][FN];
#pragma unroll
  for (int i = 0; i < FM; i++)
#pragma unroll
    for (int j = 0; j < FN; j++) acc[i][j] = zero;

  stage(0);
  stage(1);
  if constexpr (SGL == 4) asm volatile("s_waitcnt vmcnt(4)" ::: "memory");
  else                    asm volatile("s_waitcnt vmcnt(3)" ::: "memory");
  HWBAR();

  for (int t = 0; t < nt; t++) {
    const short* bX = &lX[t % 3][0];
    const short* bY = &lY[t % 3][0];
    bf16x8 xf[FM / 2], yf[FN];
#pragma unroll
    for (int i = 0; i < FM / 2; i++) {
      int row = wm * (BM / 2) + i * 16 + l15;
      xf[i] = *(const bf16x8*)&bX[row * 32 + ((l4 ^ ((row >> 1) & 3)) << 3)];
    }
#pragma unroll
    for (int j = 0; j < FN; j++) {
      int row = wn * (BN / 4) + j * 16 + l15;
      yf[j] = *(const bf16x8*)&bY[row * 32 + ((l4 ^ ((row >> 1) & 3)) << 3)];
    }
    bool st = (t + 2 < nt);
    if (st) stage(t + 2);
    HWBAR();
    __builtin_amdgcn_sched_barrier(0);
    __builtin_amdgcn_s_setprio(1);
#pragma unroll
    for (int i = 0; i < FM / 2; i++)
#pragma unroll
      for (int j = 0; j < FN; j++) acc[i][j] = MFMA16(xf[i], yf[j], acc[i][j]);
    __builtin_amdgcn_s_setprio(0);
    bf16x8 xg[FM / 2];
#pragma unroll
    for (int i = 0; i < FM / 2; i++) {
      int row = wm * (BM / 2) + (FM / 2 + i) * 16 + l15;
      xg[i] = *(const bf16x8*)&bX[row * 32 + ((l4 ^ ((row >> 1) & 3)) << 3)];
    }
    if (st) {
      if constexpr (SGL == 4) asm volatile("s_waitcnt vmcnt(4) lgkmcnt(0)" ::: "memory");
      else                    asm volatile("s_waitcnt vmcnt(3) lgkmcnt(0)" ::: "memory");
    } else {
      asm volatile("s_waitcnt vmcnt(0) lgkmcnt(0)" ::: "memory");
    }
    HWBAR();
    __builtin_amdgcn_sched_barrier(0);
    __builtin_amdgcn_s_setprio(1);
#pragma unroll
    for (int i = 0; i < FM / 2; i++)
#pragma unroll
      for (int j = 0; j < FN; j++)
        acc[FM / 2 + i][j] = MFMA16(xg[i], yf[j], acc[FM / 2 + i][j]);
    __builtin_amdgcn_s_setprio(0);
  }

#pragma unroll
  for (int i = 0; i < FM; i++) {
#pragma unroll
    for (int j = 0; j < FN; j++) {
      int m_ = m0 + wm * (BM / 2) + i * 16 + l4 * 4;
      int n = n0 + wn * (BN / 4) + j * 16 + l15;
      if (n >= N) continue;
      if (MODE == 2) {
        f32x4 s4 = *(const f32x4*)&rs[m_];
        int bb = m_ >> 11, t2 = m_ & 2047, hh = n >> 8, c = n & 255;
        if (c < 128) {
#pragma unroll
          for (int r = 0; r < 4; r++)
            ((short*)C1)[((size_t)(bb * 16 + hh) * 2048 + t2 + r) * 192 + c] =
                f2bf(acc[i][j][r] * s4[r]);
        } else {
          short4v pk;
#pragma unroll
          for (int r = 0; r < 4; r++) pk[r] = f2bf(acc[i][j][r] * s4[r]);
          *(short4v*)&((short*)C2)[((size_t)(bb * 16 + hh) * 128 + (c - 128)) * 2048 + t2] = pk;
        }
      } else if (MODE == 3) {
        int bb = m_ >> 11, t2 = m_ & 2047;
        if (n < 3072) {
          int hh = n / 192, c = n % 192;
          size_t rowb = (size_t)(bb * 16 + hh) * 2048 + t2;
          if (c < 128) {
#pragma unroll
            for (int r = 0; r < 4; r++)
              ((short*)C1)[(rowb + r) * 192 + c] = f2bf(acc[i][j][r] * 0.10411756f);
          } else {
#pragma unroll
            for (int r = 0; r < 4; r++)
              ((short*)C2)[(rowb + r) * 64 + (c - 128)] = f2bf(acc[i][j][r]);
          }
        } else if (n < 3584) {
          int c2 = n - 3072;
#pragma unroll
          for (int r = 0; r < 4; r++)
            ((short*)C3)[(size_t)(bb * 2048 + t2 + r) * 512 + c2] = f2bf(acc[i][j][r]);
        } else if (n < 3648) {
#pragma unroll
          for (int r = 0; r < 4; r++)
            ((short*)C4)[(size_t)(bb * 2048 + t2 + r) * 64 + (n - 3584)] = f2bf(acc[i][j][r]);
        }
      } else {
#pragma unroll
        for (int r = 0; r < 4; r++) {
          float v = acc[i][j][r];
          if (MODE == 0)
            ((short*)C1)[(size_t)(m_ + r) * N + n] = f2bf(v);
          else
            ((float*)C1)[(size_t)(m_ + r) * N + n] = v;
        }
      }
    }
  }
}

// ---------------- merged prep: rms row-scale + q-rope + k-rope in one launch ----------------
// blocks 0..1023:    rs[row] = rsqrt(mean(kvraw[row]^2)+eps)   (4 rows/block)
// blocks 1024..3071: q rope qrs->q_all
// blocks 3072..4095: k rope krs->k_all
__global__ __launch_bounds__(256) void prep_k(const short* __restrict__ kvraw,
                                              float* __restrict__ rs,
                                              const short* __restrict__ qrs,
                                              const short* __restrict__ krs,
                                              const float* __restrict__ freq,
                                              short* __restrict__ q_all,
                                              short* __restrict__ k_all) {
  int id = blockIdx.x;
  if (id < 1024) {
    int row = id * 4 + (threadIdx.x >> 6);
    int lane = threadIdx.x & 63;
    bf16x8 v = *(const bf16x8*)(kvraw + (size_t)row * 512 + lane * 8);
    float ss = 0.f;
#pragma unroll
    for (int j = 0; j < 8; j++) { float f = bf2f(v[j]); ss += f * f; }
#pragma unroll
    for (int m = 1; m < 64; m <<= 1) ss += __shfl_xor(ss, m);
    if (lane == 0) rs[row] = rsqrtf(ss * (1.f / 512.f) + 1e-6f);
  } else if (id < 3072) {
    int g = (id - 1024) * 256 + threadIdx.x;
    int row = g >> 3, p = g & 7;
    int t = row & 2047;
    const float scale = 0.10411756f;  // log2(e)/sqrt(192)
    bf16x8 v = *(const bf16x8*)(qrs + (size_t)row * 64 + p * 8);
    float4 fa = *(const float4*)(freq + t * 64 + p * 8);
    float4 fb = *(const float4*)(freq + t * 64 + p * 8 + 4);
    float cs[8] = {fa.x, fa.y, fa.z, fa.w, fb.x, fb.y, fb.z, fb.w};
    bf16x8 o;
#pragma unroll
    for (int j = 0; j < 4; j++) {
      float c = cs[2 * j], s = cs[2 * j + 1];
      float x0 = bf2f(v[2 * j]), x1 = bf2f(v[2 * j + 1]);
      o[2 * j] = f2bf((x0 * c - x1 * s) * scale);
      o[2 * j + 1] = f2bf((x1 * c + x0 * s) * scale);
    }
    *(bf16x8*)(q_all + (size_t)row * 192 + 128 + p * 8) = o;
  } else {
    int bt = (id - 3072) * 4 + (threadIdx.x >> 6);
    int lane = threadIdx.x & 63;
    int b = bt >> 11, t = bt & 2047;
    int p = lane >> 1;
    float c = freq[t * 64 + p * 2], s = freq[t * 64 + p * 2 + 1];
    float x0 = bf2f(krs[(size_t)bt * 64 + 2 * p]);
    float x1 = bf2f(krs[(size_t)bt * 64 + 2 * p + 1]);
    float v = (lane & 1) ? (x1 * c + x0 * s) : (x0 * c - x1 * s);
    short vb = f2bf(v);
#pragma unroll
    for (int h = 0; h < 16; h++)
      k_all[((size_t)(b * 16 + h) * 2048 + t) * 192 + 128 + lane] = vb;
  }
}

// ---------------- flash attention v10 (R18/R20-proven, ~84us): producer/consumer + triple buffer ----------------
__device__ __forceinline__ void stage6(const short* __restrict__ Kp,
                                       const short* __restrict__ VT,
                                       short* kb, short* vb, int kt, int ptid) {
#pragma unroll
  for (int c = 0; c < 6; c++) {
    int idx = c * 256 + ptid;          // boundary 832 = 13*64 -> wave-uniform branch
    if (idx < 832) {
      int r = idx / 25; if (r > 31) r = 31;
      int s = idx % 25;
      int s2 = (s >= 24) ? 0 : s;      // per-lane ADDRESS clamp, not divergence
      gl16(Kp + (size_t)(kt + r) * 192 + s2 * 8, kb + idx * 8);
    } else {
      int v = idx - 832;
      int r = v / 5; if (r > 127) r = 127;
      int s = v % 5;
      int s2 = (s >= 4) ? 0 : s;
      gl16(VT + (size_t)r * 2048 + kt + s2 * 8, vb + v * 8);
    }
  }
}

__global__ __launch_bounds__(512, 2) void attn_k(const short* __restrict__ q_all,
                                                 const short* __restrict__ k_all,
                                                 const short* __restrict__ vt,
                                                 short* __restrict__ attn_out) {
  __shared__ short kbuf[3][832 * 8];   // 3 x 13,312 B
  __shared__ short vbuf[3][704 * 8];   // 3 x 11,264 B   (total 73,728 B; 2 blocks/CU)
  int bh = blockIdx.x;
  int b = bh >> 4, h = bh & 15;
  int col = gridDim.y - 1 - blockIdx.y;  // longest first (LPT)
  int tid = threadIdx.x;
  int wave = tid >> 6, lane = tid & 63;
  int l31 = lane & 31, hi = lane >> 5;
  const bool producer = (wave >= 4);
  int qw = col * 128 + (wave & 3) * 32;  // consumer meaning
  int qrow = qw + l31;
  const short* Q = q_all + ((size_t)bh * 2048 + qrow) * 192;
  const short* Kp = k_all + (size_t)bh * 2048 * 192;
  const short* VT = vt + (size_t)bh * 128 * 2048;
  // sigma(l31): swap bits 2 and 3 (aligns S^T D-frag regs with PV B-operand k-order)
  int sig = (l31 & 19) | ((l31 >> 1) & 4) | ((l31 << 1) & 8);

  bf16x8 qf[12];
  f32x16 o[4];
  f32x16 sInit, zro;
#pragma unroll
  for (int r = 0; r < 16; r++) { sInit[r] = -28.8539f; zro[r] = 0.f; }  // -20*log2(e)
  float lsum = 0.f;
  if (!producer) {
#pragma unroll
    for (int kb = 0; kb < 12; kb++)
      qf[kb] = *(const bf16x8*)(Q + kb * 16 + hi * 8);
#pragma unroll
    for (int vb = 0; vb < 4; vb++)
#pragma unroll
      for (int r = 0; r < 16; r++) o[vb][r] = 0.f;
  }

  const int nt = (col * 128 + 128) >> 5;

  if (producer) {
    stage6(Kp, VT, kbuf[0], vbuf[0], 0, tid - 256);
    if (nt > 1) stage6(Kp, VT, kbuf[1], vbuf[1], 32, tid - 256);
    asm volatile("s_waitcnt vmcnt(6)" ::: "memory");  // buf0 complete; buf1 in flight
  }
  HWBAR();

  for (int t = 0; t < nt; t++) {
    if (producer) {
      if (t + 2 < nt) {
        stage6(Kp, VT, kbuf[(t + 2) % 3], vbuf[(t + 2) % 3], (t + 2) << 5, tid - 256);
        asm volatile("s_waitcnt vmcnt(6)" ::: "memory");  // buf[t+1] complete
      } else {
        asm volatile("s_waitcnt vmcnt(0)" ::: "memory");
      }
    } else {
      int kt = t << 5;
      int cur = t % 3;
      if (kt < qw + 32) {
        // ---- QK^T (swapped): S^T[key][q], two independent 6-chains ----
        f32x16 sc = sInit, sc2 = zro;
        __builtin_amdgcn_s_setprio(1);
#pragma unroll
        for (int kb = 0; kb < 6; kb++) {
          int c0 = 2 * kb + hi, c1 = 2 * (kb + 6) + hi;
          bf16x8 kf0 = *(const bf16x8*)&kbuf[cur][sig * 200 + (c0 << 3)];
          bf16x8 kf1 = *(const bf16x8*)&kbuf[cur][sig * 200 + (c1 << 3)];
          sc = MFMA32(kf0, qf[kb], sc);
          sc2 = MFMA32(kf1, qf[kb + 6], sc2);
        }
        __builtin_amdgcn_s_setprio(0);
#pragma unroll
        for (int r = 0; r < 16; r++) sc[r] += sc2[r];
        // ---- softmax (lane-local), pack to bf16 pairs ----
        unsigned pw[8];
        if (kt + 32 <= qw) {  // fully unmasked tile
#pragma unroll
          for (int r2 = 0; r2 < 8; r2++) {
            float pa = exp2f(sc[2 * r2]);
            float pb = exp2f(sc[2 * r2 + 1]);
            lsum += pa + pb;
            pw[r2] = cvtpk(pa, pb);
          }
        } else {
#pragma unroll
          for (int r2 = 0; r2 < 8; r2++) {
            int r = 2 * r2;
            int key = kt + (r & 3) + 4 * ((r >> 2) & 1) + 8 * hi + 16 * (r >> 3);
            float va = (key <= qrow) ? sc[r] : -1e30f;
            float vb2 = (key + 1 <= qrow) ? sc[r + 1] : -1e30f;
            float pa = exp2f(va);
            float pb = exp2f(vb2);
            lsum += pa + pb;
            pw[r2] = cvtpk(pa, pb);
          }
        }
        union { unsigned u[4]; bf16x8 v; } p0, p1;
#pragma unroll
        for (int w = 0; w < 4; w++) { p0.u[w] = pw[w]; p1.u[w] = pw[4 + w]; }
        // ---- PV (swapped): O^T[v][q] ----
        __builtin_amdgcn_s_setprio(1);
#pragma unroll
        for (int vb = 0; vb < 4; vb++) {
          int vcol = vb * 32 + l31;
          bf16x8 vf0 = *(const bf16x8*)&vbuf[cur][vcol * 40 + (hi << 3)];
          bf16x8 vf1 = *(const bf16x8*)&vbuf[cur][vcol * 40 + ((2 + hi) << 3)];
          o[vb] = MFMA32(vf0, p0.v, o[vb]);
          o[vb] = MFMA32(vf1, p1.v, o[vb]);
        }
        __builtin_amdgcn_s_setprio(0);
      }
    }
    HWBAR();
  }

  if (!producer) {
    lsum += __shfl_xor(lsum, 32);
    float inv = 1.f / lsum;
    size_t base = ((size_t)b * 2048 + qrow) * 2048 + h * 128;
#pragma unroll
    for (int vb = 0; vb < 4; vb++) {
#pragma unroll
      for (int r2 = 0; r2 < 8; r2++) {
        int r = 2 * r2;
        int v = vb * 32 + (r & 3) + 8 * (r >> 2) + 4 * hi;
        unsigned pk2 = ((unsigned)(unsigned short)f2bf(o[vb][r] * inv)) |
                       (((unsigned)(unsigned short)f2bf(o[vb][r + 1] * inv)) << 16);
        *(unsigned*)(attn_out + base + v) = pk2;
      }
    }
  }
}

extern "C" void kernel_launch(void* const* d_in, const int* in_sizes, int n_in,
                              void* d_out, int out_size, void* d_ws, size_t ws_size,
                              hipStream_t stream) {
  const float* x = (const float*)d_in[0];
  const float* freq = (const float*)d_in[1];
  const float* Wq = (const float*)d_in[4];
  const float* Wckv = (const float*)d_in[5];
  const float* kvw = (const float*)d_in[6];
  const float* Wdkv = (const float*)d_in[7];
  const float* Wproj = (const float*)d_in[8];

  char* ws = (char*)d_ws;
  size_t off = 0;
  auto alloc = [&](size_t bytes) {
    size_t o = off;
    off += (bytes + 255) & ~(size_t)255;
    return o;
  };
  size_t o_xbf = alloc(4096ull * 2048 * 2);
  size_t o_wqc = alloc(3840ull * 2048 * 2);
  size_t o_wdkv = alloc(4096ull * 512 * 2);
  size_t o_wproj = alloc(2048ull * 2048 * 2);
  size_t o_qrs = alloc(32ull * 2048 * 64 * 2);
  size_t o_kvraw = alloc(4096ull * 512 * 2);
  size_t o_krs = alloc(4096ull * 64 * 2);
  size_t o_rs = alloc(4096ull * 4);
  size_t o_qall = alloc(32ull * 2048 * 192 * 2);
  size_t o_kall = alloc(32ull * 2048 * 192 * 2);
  size_t o_vt = alloc(32ull * 128 * 2048 * 2);
  size_t o_attn = o_xbf;  // alias: x_bf dead after GEMM1

  short* x_bf = (short*)(ws + o_xbf);
  short* wqc = (short*)(ws + o_wqc);
  short* wdkv = (short*)(ws + o_wdkv);
  short* wproj = (short*)(ws + o_wproj);
  short* qrs = (short*)(ws + o_qrs);
  short* kvraw = (short*)(ws + o_kvraw);
  short* krs = (short*)(ws + o_krs);
  float* rsb = (float*)(ws + o_rs);
  short* qall = (short*)(ws + o_qall);
  short* kall = (short*)(ws + o_kall);
  short* vtb = (short*)(ws + o_vt);
  short* attnb = (short*)(ws + o_attn);

  wcvt2_k<<<17920, 256, 0, stream>>>(x, Wq, Wckv, Wdkv, Wproj, kvw,
                                     x_bf, wqc, wdkv, wproj);

  gemm8_k<3, 256, 256, 4><<<240, 512, 0, stream>>>(x_bf, wqc, qall, qrs, kvraw, krs,
                                                   nullptr, 4096, 3712, 2048, 16);

  prep_k<<<4096, 256, 0, stream>>>(kvraw, rsb, qrs, krs, freq, qall, kall);

  // GEMM2: A = kvraw (unnormalized); rmsnorm row-scale rs applied in epilogue;
  // kv_norm_w folded into wdkv at wcvt time.
  gemm8_k<2, 256, 256, 4><<<256, 512, 0, stream>>>(kvraw, wdkv, kall, vtb, nullptr, nullptr,
                                                   rsb, 4096, 4096, 512, 16);

  attn_k<<<dim3(32, 16), 512, 0, stream>>>(qall, kall, vtb, attnb);

  gemm8_k<1, 128, 256, 3><<<256, 512, 0, stream>>>(attnb, wproj, d_out, nullptr, nullptr,
                                                   nullptr, nullptr, 4096, 2048, 2048, 32);
}

// Round 22
// 257.198 us; speedup vs baseline: 1.0109x; 1.0109x over previous
//
#include <hip/hip_runtime.h>
#include <hip/hip_bf16.h>
#include <math.h>

// MLA forward: B=2 T=2048 C=2048 H=16 NOPE=128 ROPE=64 VD=128 LORA=512 QK=192

typedef short bf16x8 __attribute__((ext_vector_type(8)));
typedef short short4v __attribute__((ext_vector_type(4)));
typedef float f32x4 __attribute__((ext_vector_type(4)));
typedef float f32x16 __attribute__((ext_vector_type(16)));

#define MFMA16(a, b, c) __builtin_amdgcn_mfma_f32_16x16x32_bf16(a, b, c, 0, 0, 0)
#define MFMA32(a, b, c) __builtin_amdgcn_mfma_f32_32x32x16_bf16(a, b, c, 0, 0, 0)

__device__ __forceinline__ short f2bf(float f) {
  union { float f; unsigned u; } v; v.f = f;
  unsigned r = v.u + 0x7fffu + ((v.u >> 16) & 1u);
  return (short)(r >> 16);
}
__device__ __forceinline__ float bf2f(short s) {
  union { unsigned u; float f; } v;
  v.u = ((unsigned)(unsigned short)s) << 16;
  return v.f;
}
__device__ __forceinline__ unsigned cvtpk(float a, float b) {
  unsigned r;
  asm("v_cvt_pk_bf16_f32 %0, %1, %2" : "=v"(r) : "v"(a), "v"(b));
  return r;
}
__device__ __forceinline__ void gl16(const void* g, void* l) {
  __builtin_amdgcn_global_load_lds(
      (const __attribute__((address_space(1))) unsigned int*)g,
      (__attribute__((address_space(3))) unsigned int*)l, 16, 0, 0);
}
#define CFENCE() asm volatile("" ::: "memory")
#define HWBAR()  do { CFENCE(); __builtin_amdgcn_s_barrier(); CFENCE(); } while (0)

// ---------------- merged x-cvt + weight transpose+cvt: 5 jobs in one launch ----------------
__global__ __launch_bounds__(256) void wcvt2_k(const float* __restrict__ x,
                                               const float* __restrict__ Wq,
                                               const float* __restrict__ Wckv,
                                               const float* __restrict__ Wdkv,
                                               const float* __restrict__ Wproj,
                                               short* __restrict__ x_bf,
                                               short* __restrict__ wqc,
                                               short* __restrict__ wdkv,
                                               short* __restrict__ wproj) {
  __shared__ float tile[32][33];
  int id = blockIdx.x;
  if (id < 4096) {
    int i = (id * 256 + threadIdx.x) * 8;
    float4 a = *(const float4*)(x + i);
    float4 b = *(const float4*)(x + i + 4);
    bf16x8 o;
    o[0] = f2bf(a.x); o[1] = f2bf(a.y); o[2] = f2bf(a.z); o[3] = f2bf(a.w);
    o[4] = f2bf(b.x); o[5] = f2bf(b.y); o[6] = f2bf(b.z); o[7] = f2bf(b.w);
    *(bf16x8*)(x_bf + i) = o;
    return;
  }
  id -= 4096;
  const float* W; short* out; int K, N, gx, row_off, idx;
  if (id < 6144)      { idx = id;        W = Wq;    out = wqc;   K = 2048; N = 3072; gx = 64; row_off = 0; }
  else if (id < 7680) { idx = id - 6144; W = Wckv;  out = wqc;   K = 2048; N = 576;  gx = 64; row_off = 3072; }
  else if (id < 9728) { idx = id - 7680; W = Wdkv;  out = wdkv;  K = 512;  N = 4096; gx = 16; row_off = 0; }
  else                { idx = id - 9728; W = Wproj; out = wproj; K = 2048; N = 2048; gx = 64; row_off = 0; }
  int k0 = (idx % gx) * 32, n0 = (idx / gx) * 32;
  int tx = threadIdx.x & 31, ty = threadIdx.x >> 5;
#pragma unroll
  for (int j = 0; j < 4; j++) {
    int k = k0 + ty + j * 8, n = n0 + tx;
    tile[ty + j * 8][tx] = (n < N) ? W[(size_t)k * N + n] : 0.f;
  }
  __syncthreads();
#pragma unroll
  for (int j = 0; j < 4; j++) {
    int n = n0 + ty + j * 8;
    out[(size_t)(row_off + n) * K + k0 + tx] = f2bf(tile[tx][ty + j * 8]);
  }
}

// ---------------- GEMM: triple-buffer counted-vmcnt phase-split (proven loop) ----------------
template <int MODE, int BM, int BN, int SGL>
__global__ __launch_bounds__(512, 2) void gemm8_k(const short* __restrict__ A,
                                                  const short* __restrict__ Bt,
                                                  void* __restrict__ C1,
                                                  void* __restrict__ C2,
                                                  void* __restrict__ C3,
                                                  void* __restrict__ C4,
                                                  int M, int N, int K, int nbx) {
  constexpr int FM = BM / 32;
  constexpr int FN = BN / 64;
  constexpr int XCH = (BM * 4) / 512;
  constexpr int YCH = (BN * 4) / 512;
  __shared__ short lX[3][BM * 32];
  __shared__ short lY[3][BN * 32];

  const int nwg = gridDim.x;
  const int cpx = nwg >> 3;
  const int swz = (blockIdx.x & 7) * cpx + (blockIdx.x >> 3);
  const int bx = swz % nbx, by = swz / nbx;
  const int m0 = bx * BM, n0 = by * BN;
  const int tid = threadIdx.x, lane = tid & 63, wave = tid >> 6;
  const int wm = wave >> 2, wn = wave & 3;
  const int l15 = lane & 15, l4 = lane >> 4;
  const int nt = K >> 5;

  auto stage = [&](int t) {
    int kk = t << 5;
    short* bX = &lX[t % 3][0];
    short* bY = &lY[t % 3][0];
#pragma unroll
    for (int c = 0; c < XCH; c++) {
      int idx = c * 512 + tid;
      int row = idx >> 2, seg = idx & 3;
      gl16(A + (size_t)(m0 + row) * K + kk + ((seg ^ ((row >> 1) & 3)) << 3),
           bX + idx * 8);
    }
#pragma unroll
    for (int c = 0; c < YCH; c++) {
      int idx = c * 512 + tid;
      int row = idx >> 2, seg = idx & 3;
      gl16(Bt + (size_t)(n0 + row) * K + kk + ((seg ^ ((row >> 1) & 3)) << 3),
           bY + idx * 8);
    }
  };

  f32x4 zero = {0.f, 0.f, 0.f, 0.f};
  f32x4 acc[FM][FN];
#pragma unroll
  for (int i = 0; i < FM; i++)
#pragma unroll
    for (int j = 0; j < FN; j++) acc[i][j] = zero;

  stage(0);
  stage(1);
  if constexpr (SGL == 4) asm volatile("s_waitcnt vmcnt(4)" ::: "memory");
  else                    asm volatile("s_waitcnt vmcnt(3)" ::: "memory");
  HWBAR();

  for (int t = 0; t < nt; t++) {
    const short* bX = &lX[t % 3][0];
    const short* bY = &lY[t % 3][0];
    bf16x8 xf[FM / 2], yf[FN];
#pragma unroll
    for (int i = 0; i < FM / 2; i++) {
      int row = wm * (BM / 2) + i * 16 + l15;
      xf[i] = *(const bf16x8*)&bX[row * 32 + ((l4 ^ ((row >> 1) & 3)) << 3)];
    }
#pragma unroll
    for (int j = 0; j < FN; j++) {
      int row = wn * (BN / 4) + j * 16 + l15;
      yf[j] = *(const bf16x8*)&bY[row * 32 + ((l4 ^ ((row >> 1) & 3)) << 3)];
    }
    bool st = (t + 2 < nt);
    if (st) stage(t + 2);
    HWBAR();
    __builtin_amdgcn_sched_barrier(0);
    __builtin_amdgcn_s_setprio(1);
#pragma unroll
    for (int i = 0; i < FM / 2; i++)
#pragma unroll
      for (int j = 0; j < FN; j++) acc[i][j] = MFMA16(xf[i], yf[j], acc[i][j]);
    __builtin_amdgcn_s_setprio(0);
    bf16x8 xg[FM / 2];
#pragma unroll
    for (int i = 0; i < FM / 2; i++) {
      int row = wm * (BM / 2) + (FM / 2 + i) * 16 + l15;
      xg[i] = *(const bf16x8*)&bX[row * 32 + ((l4 ^ ((row >> 1) & 3)) << 3)];
    }
    if (st) {
      if constexpr (SGL == 4) asm volatile("s_waitcnt vmcnt(4) lgkmcnt(0)" ::: "memory");
      else                    asm volatile("s_waitcnt vmcnt(3) lgkmcnt(0)" ::: "memory");
    } else {
      asm volatile("s_waitcnt vmcnt(0) lgkmcnt(0)" ::: "memory");
    }
    HWBAR();
    __builtin_amdgcn_sched_barrier(0);
    __builtin_amdgcn_s_setprio(1);
#pragma unroll
    for (int i = 0; i < FM / 2; i++)
#pragma unroll
      for (int j = 0; j < FN; j++)
        acc[FM / 2 + i][j] = MFMA16(xg[i], yf[j], acc[FM / 2 + i][j]);
    __builtin_amdgcn_s_setprio(0);
  }

#pragma unroll
  for (int i = 0; i < FM; i++) {
#pragma unroll
    for (int j = 0; j < FN; j++) {
      int m_ = m0 + wm * (BM / 2) + i * 16 + l4 * 4;
      int n = n0 + wn * (BN / 4) + j * 16 + l15;
      if (n >= N) continue;
      if (MODE == 2) {
        int bb = m_ >> 11, t2 = m_ & 2047, hh = n >> 8, c = n & 255;
        if (c < 128) {
#pragma unroll
          for (int r = 0; r < 4; r++)
            ((short*)C1)[((size_t)(bb * 16 + hh) * 2048 + t2 + r) * 192 + c] =
                f2bf(acc[i][j][r]);
        } else {
          short4v pk;
#pragma unroll
          for (int r = 0; r < 4; r++) pk[r] = f2bf(acc[i][j][r]);
          *(short4v*)&((short*)C2)[((size_t)(bb * 16 + hh) * 128 + (c - 128)) * 2048 + t2] = pk;
        }
      } else if (MODE == 3) {
        int bb = m_ >> 11, t2 = m_ & 2047;
        if (n < 3072) {
          int hh = n / 192, c = n % 192;
          size_t rowb = (size_t)(bb * 16 + hh) * 2048 + t2;
          if (c < 128) {
#pragma unroll
            for (int r = 0; r < 4; r++)
              ((short*)C1)[(rowb + r) * 192 + c] = f2bf(acc[i][j][r] * 0.10411756f);
          } else {
#pragma unroll
            for (int r = 0; r < 4; r++)
              ((short*)C2)[(rowb + r) * 64 + (c - 128)] = f2bf(acc[i][j][r]);
          }
        } else if (n < 3584) {
          int c2 = n - 3072;
#pragma unroll
          for (int r = 0; r < 4; r++)
            ((short*)C3)[(size_t)(bb * 2048 + t2 + r) * 512 + c2] = f2bf(acc[i][j][r]);
        } else if (n < 3648) {
#pragma unroll
          for (int r = 0; r < 4; r++)
            ((short*)C4)[(size_t)(bb * 2048 + t2 + r) * 64 + (n - 3584)] = f2bf(acc[i][j][r]);
        }
      } else {
#pragma unroll
        for (int r = 0; r < 4; r++) {
          float v = acc[i][j][r];
          if (MODE == 0)
            ((short*)C1)[(size_t)(m_ + r) * N + n] = f2bf(v);
          else
            ((float*)C1)[(size_t)(m_ + r) * N + n] = v;
        }
      }
    }
  }
}

// ---------------- merged prep: rmsnorm + q-rope + k-rope in one launch ----------------
__global__ __launch_bounds__(256) void prep_k(const short* __restrict__ kvraw,
                                              const float* __restrict__ kvw,
                                              short* __restrict__ kvlat,
                                              const short* __restrict__ qrs,
                                              const short* __restrict__ krs,
                                              const float* __restrict__ freq,
                                              short* __restrict__ q_all,
                                              short* __restrict__ k_all) {
  int id = blockIdx.x;
  if (id < 1024) {
    int row = id * 4 + (threadIdx.x >> 6);
    int lane = threadIdx.x & 63;
    bf16x8 v = *(const bf16x8*)(kvraw + (size_t)row * 512 + lane * 8);
    float f[8];
    float ss = 0.f;
#pragma unroll
    for (int j = 0; j < 8; j++) { f[j] = bf2f(v[j]); ss += f[j] * f[j]; }
#pragma unroll
    for (int m = 1; m < 64; m <<= 1) ss += __shfl_xor(ss, m);
    float r = rsqrtf(ss * (1.f / 512.f) + 1e-6f);
    bf16x8 o;
#pragma unroll
    for (int j = 0; j < 8; j++) o[j] = f2bf(f[j] * r * kvw[lane * 8 + j]);
    *(bf16x8*)(kvlat + (size_t)row * 512 + lane * 8) = o;
  } else if (id < 3072) {
    int g = (id - 1024) * 256 + threadIdx.x;
    int row = g >> 3, p = g & 7;
    int t = row & 2047;
    const float scale = 0.10411756f;  // log2(e)/sqrt(192)
    bf16x8 v = *(const bf16x8*)(qrs + (size_t)row * 64 + p * 8);
    float4 fa = *(const float4*)(freq + t * 64 + p * 8);
    float4 fb = *(const float4*)(freq + t * 64 + p * 8 + 4);
    float cs[8] = {fa.x, fa.y, fa.z, fa.w, fb.x, fb.y, fb.z, fb.w};
    bf16x8 o;
#pragma unroll
    for (int j = 0; j < 4; j++) {
      float c = cs[2 * j], s = cs[2 * j + 1];
      float x0 = bf2f(v[2 * j]), x1 = bf2f(v[2 * j + 1]);
      o[2 * j] = f2bf((x0 * c - x1 * s) * scale);
      o[2 * j + 1] = f2bf((x1 * c + x0 * s) * scale);
    }
    *(bf16x8*)(q_all + (size_t)row * 192 + 128 + p * 8) = o;
  } else {
    int bt = (id - 3072) * 4 + (threadIdx.x >> 6);
    int lane = threadIdx.x & 63;
    int b = bt >> 11, t = bt & 2047;
    int p = lane >> 1;
    float c = freq[t * 64 + p * 2], s = freq[t * 64 + p * 2 + 1];
    float x0 = bf2f(krs[(size_t)bt * 64 + 2 * p]);
    float x1 = bf2f(krs[(size_t)bt * 64 + 2 * p + 1]);
    float v = (lane & 1) ? (x1 * c + x0 * s) : (x0 * c - x1 * s);
    short vb = f2bf(v);
#pragma unroll
    for (int h = 0; h < 16; h++)
      k_all[((size_t)(b * 16 + h) * 2048 + t) * 192 + 128 + lane] = vb;
  }
}

// ---------------- flash attention v10 (R18/R20-proven, ~84us) ----------------
__device__ __forceinline__ void stage6(const short* __restrict__ Kp,
                                       const short* __restrict__ VT,
                                       short* kb, short* vb, int kt, int ptid) {
#pragma unroll
  for (int c = 0; c < 6; c++) {
    int idx = c * 256 + ptid;          // boundary 832 = 13*64 -> wave-uniform branch
    if (idx < 832) {
      int r = idx / 25; if (r > 31) r = 31;
      int s = idx % 25;
      int s2 = (s >= 24) ? 0 : s;      // per-lane ADDRESS clamp, not divergence
      gl16(Kp + (size_t)(kt + r) * 192 + s2 * 8, kb + idx * 8);
    } else {
      int v = idx - 832;
      int r = v / 5; if (r > 127) r = 127;
      int s = v % 5;
      int s2 = (s >= 4) ? 0 : s;
      gl16(VT + (size_t)r * 2048 + kt + s2 * 8, vb + v * 8);
    }
  }
}

__global__ __launch_bounds__(512, 2) void attn_k(const short* __restrict__ q_all,
                                                 const short* __restrict__ k_all,
                                                 const short* __restrict__ vt,
                                                 short* __restrict__ attn_out) {
  __shared__ short kbuf[3][832 * 8];   // 3 x 13,312 B
  __shared__ short vbuf[3][704 * 8];   // 3 x 11,264 B   (total 73,728 B; 2 blocks/CU)
  int bh = blockIdx.x;
  int b = bh >> 4, h = bh & 15;
  int col = gridDim.y - 1 - blockIdx.y;  // longest first (LPT)
  int tid = threadIdx.x;
  int wave = tid >> 6, lane = tid & 63;
  int l31 = lane & 31, hi = lane >> 5;
  const bool producer = (wave >= 4);
  int qw = col * 128 + (wave & 3) * 32;  // consumer meaning
  int qrow = qw + l31;
  const short* Q = q_all + ((size_t)bh * 2048 + qrow) * 192;
  const short* Kp = k_all + (size_t)bh * 2048 * 192;
  const short* VT = vt + (size_t)bh * 128 * 2048;
  // sigma(l31): swap bits 2 and 3 (aligns S^T D-frag regs with PV B-operand k-order)
  int sig = (l31 & 19) | ((l31 >> 1) & 4) | ((l31 << 1) & 8);

  bf16x8 qf[12];
  f32x16 o[4];
  f32x16 sInit, zro;
#pragma unroll
  for (int r = 0; r < 16; r++) { sInit[r] = -28.8539f; zro[r] = 0.f; }  // -20*log2(e)
  float lsum = 0.f;
  if (!producer) {
#pragma unroll
    for (int kb = 0; kb < 12; kb++)
      qf[kb] = *(const bf16x8*)(Q + kb * 16 + hi * 8);
#pragma unroll
    for (int vb = 0; vb < 4; vb++)
#pragma unroll
      for (int r = 0; r < 16; r++) o[vb][r] = 0.f;
  }

  const int nt = (col * 128 + 128) >> 5;

  if (producer) {
    stage6(Kp, VT, kbuf[0], vbuf[0], 0, tid - 256);
    if (nt > 1) stage6(Kp, VT, kbuf[1], vbuf[1], 32, tid - 256);
    asm volatile("s_waitcnt vmcnt(6)" ::: "memory");  // buf0 complete; buf1 in flight
  }
  HWBAR();

  for (int t = 0; t < nt; t++) {
    if (producer) {
      if (t + 2 < nt) {
        stage6(Kp, VT, kbuf[(t + 2) % 3], vbuf[(t + 2) % 3], (t + 2) << 5, tid - 256);
        asm volatile("s_waitcnt vmcnt(6)" ::: "memory");  // buf[t+1] complete
      } else {
        asm volatile("s_waitcnt vmcnt(0)" ::: "memory");
      }
    } else {
      int kt = t << 5;
      int cur = t % 3;
      if (kt < qw + 32) {
        // ---- QK^T (swapped): S^T[key][q], two independent 6-chains ----
        f32x16 sc = sInit, sc2 = zro;
        __builtin_amdgcn_s_setprio(1);
#pragma unroll
        for (int kb = 0; kb < 6; kb++) {
          int c0 = 2 * kb + hi, c1 = 2 * (kb + 6) + hi;
          bf16x8 kf0 = *(const bf16x8*)&kbuf[cur][sig * 200 + (c0 << 3)];
          bf16x8 kf1 = *(const bf16x8*)&kbuf[cur][sig * 200 + (c1 << 3)];
          sc = MFMA32(kf0, qf[kb], sc);
          sc2 = MFMA32(kf1, qf[kb + 6], sc2);
        }
        __builtin_amdgcn_s_setprio(0);
#pragma unroll
        for (int r = 0; r < 16; r++) sc[r] += sc2[r];
        // ---- softmax (lane-local), pack to bf16 pairs ----
        unsigned pw[8];
        if (kt + 32 <= qw) {  // fully unmasked tile
#pragma unroll
          for (int r2 = 0; r2 < 8; r2++) {
            float pa = exp2f(sc[2 * r2]);
            float pb = exp2f(sc[2 * r2 + 1]);
            lsum += pa + pb;
            pw[r2] = cvtpk(pa, pb);
          }
        } else {
#pragma unroll
          for (int r2 = 0; r2 < 8; r2++) {
            int r = 2 * r2;
            int key = kt + (r & 3) + 4 * ((r >> 2) & 1) + 8 * hi + 16 * (r >> 3);
            float va = (key <= qrow) ? sc[r] : -1e30f;
            float vb2 = (key + 1 <= qrow) ? sc[r + 1] : -1e30f;
            float pa = exp2f(va);
            float pb = exp2f(vb2);
            lsum += pa + pb;
            pw[r2] = cvtpk(pa, pb);
          }
        }
        union { unsigned u[4]; bf16x8 v; } p0, p1;
#pragma unroll
        for (int w = 0; w < 4; w++) { p0.u[w] = pw[w]; p1.u[w] = pw[4 + w]; }
        // ---- PV (swapped): O^T[v][q] ----
        __builtin_amdgcn_s_setprio(1);
#pragma unroll
        for (int vb = 0; vb < 4; vb++) {
          int vcol = vb * 32 + l31;
          bf16x8 vf0 = *(const bf16x8*)&vbuf[cur][vcol * 40 + (hi << 3)];
          bf16x8 vf1 = *(const bf16x8*)&vbuf[cur][vcol * 40 + ((2 + hi) << 3)];
          o[vb] = MFMA32(vf0, p0.v, o[vb]);
          o[vb] = MFMA32(vf1, p1.v, o[vb]);
        }
        __builtin_amdgcn_s_setprio(0);
      }
    }
    HWBAR();
  }

  if (!producer) {
    lsum += __shfl_xor(lsum, 32);
    float inv = 1.f / lsum;
    size_t base = ((size_t)b * 2048 + qrow) * 2048 + h * 128;
#pragma unroll
    for (int vb = 0; vb < 4; vb++) {
#pragma unroll
      for (int r2 = 0; r2 < 8; r2++) {
        int r = 2 * r2;
        int v = vb * 32 + (r & 3) + 8 * (r >> 2) + 4 * hi;
        unsigned pk2 = ((unsigned)(unsigned short)f2bf(o[vb][r] * inv)) |
                       (((unsigned)(unsigned short)f2bf(o[vb][r + 1] * inv)) << 16);
        *(unsigned*)(attn_out + base + v) = pk2;
      }
    }
  }
}

extern "C" void kernel_launch(void* const* d_in, const int* in_sizes, int n_in,
                              void* d_out, int out_size, void* d_ws, size_t ws_size,
                              hipStream_t stream) {
  const float* x = (const float*)d_in[0];
  const float* freq = (const float*)d_in[1];
  const float* Wq = (const float*)d_in[4];
  const float* Wckv = (const float*)d_in[5];
  const float* kvw = (const float*)d_in[6];
  const float* Wdkv = (const float*)d_in[7];
  const float* Wproj = (const float*)d_in[8];

  char* ws = (char*)d_ws;
  size_t off = 0;
  auto alloc = [&](size_t bytes) {
    size_t o = off;
    off += (bytes + 255) & ~(size_t)255;
    return o;
  };
  size_t o_xbf = alloc(4096ull * 2048 * 2);
  size_t o_wqc = alloc(3840ull * 2048 * 2);
  size_t o_wdkv = alloc(4096ull * 512 * 2);
  size_t o_wproj = alloc(2048ull * 2048 * 2);
  size_t o_qrs = alloc(32ull * 2048 * 64 * 2);
  size_t o_kvraw = alloc(4096ull * 512 * 2);
  size_t o_krs = alloc(4096ull * 64 * 2);
  size_t o_kvlat = alloc(4096ull * 512 * 2);
  size_t o_qall = alloc(32ull * 2048 * 192 * 2);
  size_t o_kall = alloc(32ull * 2048 * 192 * 2);
  size_t o_vt = alloc(32ull * 128 * 2048 * 2);
  size_t o_attn = o_xbf;  // alias: x_bf dead after GEMM1

  short* x_bf = (short*)(ws + o_xbf);
  short* wqc = (short*)(ws + o_wqc);
  short* wdkv = (short*)(ws + o_wdkv);
  short* wproj = (short*)(ws + o_wproj);
  short* qrs = (short*)(ws + o_qrs);
  short* kvraw = (short*)(ws + o_kvraw);
  short* krs = (short*)(ws + o_krs);
  short* kvlat = (short*)(ws + o_kvlat);
  short* qall = (short*)(ws + o_qall);
  short* kall = (short*)(ws + o_kall);
  short* vtb = (short*)(ws + o_vt);
  short* attnb = (short*)(ws + o_attn);

  wcvt2_k<<<17920, 256, 0, stream>>>(x, Wq, Wckv, Wdkv, Wproj, x_bf, wqc, wdkv, wproj);

  // GEMM1: 128x256 tile -> 72KB LDS -> 2 blocks/CU (was 1 at 256x256); grid 32x15=480
  gemm8_k<3, 128, 256, 3><<<480, 512, 0, stream>>>(x_bf, wqc, qall, qrs, kvraw, krs,
                                                   4096, 3712, 2048, 32);

  prep_k<<<4096, 256, 0, stream>>>(kvraw, kvw, kvlat, qrs, krs, freq, qall, kall);

  // GEMM2: 128x256 tile; grid 32x16=512
  gemm8_k<2, 128, 256, 3><<<512, 512, 0, stream>>>(kvlat, wdkv, kall, vtb, nullptr, nullptr,
                                                   4096, 4096, 512, 32);

  attn_k<<<dim3(32, 16), 512, 0, stream>>>(qall, kall, vtb, attnb);

  gemm8_k<1, 128, 256, 3><<<256, 512, 0, stream>>>(attnb, wproj, d_out, nullptr, nullptr, nullptr,
                                                   4096, 2048, 2048, 32);
}

// Round 23
// 256.281 us; speedup vs baseline: 1.0145x; 1.0036x over previous
//
#include <hip/hip_runtime.h>
#include <hip/hip_bf16.h>
#include <math.h>

// MLA forward: B=2 T=2048 C=2048 H=16 NOPE=128 ROPE=64 VD=128 LORA=512 QK=192
// Final configuration (session best, R18-verified 256.3us):
//  - 5-launch pipeline: wcvt2 -> GEMM1(fused scatter) -> prep -> GEMM2(scatter) -> attn -> GEMM3
//  - GEMMs: 256/128x256 triple-buffer counted-vmcnt phase-split, XCD swizzle, odd XOR-swizzled LDS
//  - attn: producer/consumer wave specialization, 32x32 swapped lane-local softmax,
//          odd-stride LDS (0 bank conflicts), triple buffer, counted vmcnt

typedef short bf16x8 __attribute__((ext_vector_type(8)));
typedef short short4v __attribute__((ext_vector_type(4)));
typedef float f32x4 __attribute__((ext_vector_type(4)));
typedef float f32x16 __attribute__((ext_vector_type(16)));

#define MFMA16(a, b, c) __builtin_amdgcn_mfma_f32_16x16x32_bf16(a, b, c, 0, 0, 0)
#define MFMA32(a, b, c) __builtin_amdgcn_mfma_f32_32x32x16_bf16(a, b, c, 0, 0, 0)

__device__ __forceinline__ short f2bf(float f) {
  union { float f; unsigned u; } v; v.f = f;
  unsigned r = v.u + 0x7fffu + ((v.u >> 16) & 1u);
  return (short)(r >> 16);
}
__device__ __forceinline__ float bf2f(short s) {
  union { unsigned u; float f; } v;
  v.u = ((unsigned)(unsigned short)s) << 16;
  return v.f;
}
__device__ __forceinline__ unsigned cvtpk(float a, float b) {
  unsigned r;
  asm("v_cvt_pk_bf16_f32 %0, %1, %2" : "=v"(r) : "v"(a), "v"(b));
  return r;
}
__device__ __forceinline__ void gl16(const void* g, void* l) {
  __builtin_amdgcn_global_load_lds(
      (const __attribute__((address_space(1))) unsigned int*)g,
      (__attribute__((address_space(3))) unsigned int*)l, 16, 0, 0);
}
#define CFENCE() asm volatile("" ::: "memory")
#define HWBAR()  do { CFENCE(); __builtin_amdgcn_s_barrier(); CFENCE(); } while (0)

// ---------------- merged x-cvt + weight transpose+cvt: 5 jobs in one launch ----------------
__global__ __launch_bounds__(256) void wcvt2_k(const float* __restrict__ x,
                                               const float* __restrict__ Wq,
                                               const float* __restrict__ Wckv,
                                               const float* __restrict__ Wdkv,
                                               const float* __restrict__ Wproj,
                                               short* __restrict__ x_bf,
                                               short* __restrict__ wqc,
                                               short* __restrict__ wdkv,
                                               short* __restrict__ wproj) {
  __shared__ float tile[32][33];
  int id = blockIdx.x;
  if (id < 4096) {
    int i = (id * 256 + threadIdx.x) * 8;
    float4 a = *(const float4*)(x + i);
    float4 b = *(const float4*)(x + i + 4);
    bf16x8 o;
    o[0] = f2bf(a.x); o[1] = f2bf(a.y); o[2] = f2bf(a.z); o[3] = f2bf(a.w);
    o[4] = f2bf(b.x); o[5] = f2bf(b.y); o[6] = f2bf(b.z); o[7] = f2bf(b.w);
    *(bf16x8*)(x_bf + i) = o;
    return;
  }
  id -= 4096;
  const float* W; short* out; int K, N, gx, row_off, idx;
  if (id < 6144)      { idx = id;        W = Wq;    out = wqc;   K = 2048; N = 3072; gx = 64; row_off = 0; }
  else if (id < 7680) { idx = id - 6144; W = Wckv;  out = wqc;   K = 2048; N = 576;  gx = 64; row_off = 3072; }
  else if (id < 9728) { idx = id - 7680; W = Wdkv;  out = wdkv;  K = 512;  N = 4096; gx = 16; row_off = 0; }
  else                { idx = id - 9728; W = Wproj; out = wproj; K = 2048; N = 2048; gx = 64; row_off = 0; }
  int k0 = (idx % gx) * 32, n0 = (idx / gx) * 32;
  int tx = threadIdx.x & 31, ty = threadIdx.x >> 5;
#pragma unroll
  for (int j = 0; j < 4; j++) {
    int k = k0 + ty + j * 8, n = n0 + tx;
    tile[ty + j * 8][tx] = (n < N) ? W[(size_t)k * N + n] : 0.f;
  }
  __syncthreads();
#pragma unroll
  for (int j = 0; j < 4; j++) {
    int n = n0 + ty + j * 8;
    out[(size_t)(row_off + n) * K + k0 + tx] = f2bf(tile[tx][ty + j * 8]);
  }
}

// ---------------- GEMM: triple-buffer counted-vmcnt phase-split (proven loop) ----------------
template <int MODE, int BM, int BN, int SGL>
__global__ __launch_bounds__(512, 2) void gemm8_k(const short* __restrict__ A,
                                                  const short* __restrict__ Bt,
                                                  void* __restrict__ C1,
                                                  void* __restrict__ C2,
                                                  void* __restrict__ C3,
                                                  void* __restrict__ C4,
                                                  int M, int N, int K, int nbx) {
  constexpr int FM = BM / 32;
  constexpr int FN = BN / 64;
  constexpr int XCH = (BM * 4) / 512;
  constexpr int YCH = (BN * 4) / 512;
  __shared__ short lX[3][BM * 32];
  __shared__ short lY[3][BN * 32];

  const int nwg = gridDim.x;
  const int cpx = nwg >> 3;
  const int swz = (blockIdx.x & 7) * cpx + (blockIdx.x >> 3);
  const int bx = swz % nbx, by = swz / nbx;
  const int m0 = bx * BM, n0 = by * BN;
  const int tid = threadIdx.x, lane = tid & 63, wave = tid >> 6;
  const int wm = wave >> 2, wn = wave & 3;
  const int l15 = lane & 15, l4 = lane >> 4;
  const int nt = K >> 5;

  auto stage = [&](int t) {
    int kk = t << 5;
    short* bX = &lX[t % 3][0];
    short* bY = &lY[t % 3][0];
#pragma unroll
    for (int c = 0; c < XCH; c++) {
      int idx = c * 512 + tid;
      int row = idx >> 2, seg = idx & 3;
      gl16(A + (size_t)(m0 + row) * K + kk + ((seg ^ ((row >> 1) & 3)) << 3),
           bX + idx * 8);
    }
#pragma unroll
    for (int c = 0; c < YCH; c++) {
      int idx = c * 512 + tid;
      int row = idx >> 2, seg = idx & 3;
      gl16(Bt + (size_t)(n0 + row) * K + kk + ((seg ^ ((row >> 1) & 3)) << 3),
           bY + idx * 8);
    }
  };

  f32x4 zero = {0.f, 0.f, 0.f, 0.f};
  f32x4 acc[FM][FN];
#pragma unroll
  for (int i = 0; i < FM; i++)
#pragma unroll
    for (int j = 0; j < FN; j++) acc[i][j] = zero;

  stage(0);
  stage(1);
  if constexpr (SGL == 4) asm volatile("s_waitcnt vmcnt(4)" ::: "memory");
  else                    asm volatile("s_waitcnt vmcnt(3)" ::: "memory");
  HWBAR();

  for (int t = 0; t < nt; t++) {
    const short* bX = &lX[t % 3][0];
    const short* bY = &lY[t % 3][0];
    bf16x8 xf[FM / 2], yf[FN];
#pragma unroll
    for (int i = 0; i < FM / 2; i++) {
      int row = wm * (BM / 2) + i * 16 + l15;
      xf[i] = *(const bf16x8*)&bX[row * 32 + ((l4 ^ ((row >> 1) & 3)) << 3)];
    }
#pragma unroll
    for (int j = 0; j < FN; j++) {
      int row = wn * (BN / 4) + j * 16 + l15;
      yf[j] = *(const bf16x8*)&bY[row * 32 + ((l4 ^ ((row >> 1) & 3)) << 3)];
    }
    bool st = (t + 2 < nt);
    if (st) stage(t + 2);
    HWBAR();
    __builtin_amdgcn_sched_barrier(0);
    __builtin_amdgcn_s_setprio(1);
#pragma unroll
    for (int i = 0; i < FM / 2; i++)
#pragma unroll
      for (int j = 0; j < FN; j++) acc[i][j] = MFMA16(xf[i], yf[j], acc[i][j]);
    __builtin_amdgcn_s_setprio(0);
    bf16x8 xg[FM / 2];
#pragma unroll
    for (int i = 0; i < FM / 2; i++) {
      int row = wm * (BM / 2) + (FM / 2 + i) * 16 + l15;
      xg[i] = *(const bf16x8*)&bX[row * 32 + ((l4 ^ ((row >> 1) & 3)) << 3)];
    }
    if (st) {
      if constexpr (SGL == 4) asm volatile("s_waitcnt vmcnt(4) lgkmcnt(0)" ::: "memory");
      else                    asm volatile("s_waitcnt vmcnt(3) lgkmcnt(0)" ::: "memory");
    } else {
      asm volatile("s_waitcnt vmcnt(0) lgkmcnt(0)" ::: "memory");
    }
    HWBAR();
    __builtin_amdgcn_sched_barrier(0);
    __builtin_amdgcn_s_setprio(1);
#pragma unroll
    for (int i = 0; i < FM / 2; i++)
#pragma unroll
      for (int j = 0; j < FN; j++)
        acc[FM / 2 + i][j] = MFMA16(xg[i], yf[j], acc[FM / 2 + i][j]);
    __builtin_amdgcn_s_setprio(0);
  }

#pragma unroll
  for (int i = 0; i < FM; i++) {
#pragma unroll
    for (int j = 0; j < FN; j++) {
      int m_ = m0 + wm * (BM / 2) + i * 16 + l4 * 4;
      int n = n0 + wn * (BN / 4) + j * 16 + l15;
      if (n >= N) continue;
      if (MODE == 2) {
        int bb = m_ >> 11, t2 = m_ & 2047, hh = n >> 8, c = n & 255;
        if (c < 128) {
#pragma unroll
          for (int r = 0; r < 4; r++)
            ((short*)C1)[((size_t)(bb * 16 + hh) * 2048 + t2 + r) * 192 + c] =
                f2bf(acc[i][j][r]);
        } else {
          short4v pk;
#pragma unroll
          for (int r = 0; r < 4; r++) pk[r] = f2bf(acc[i][j][r]);
          *(short4v*)&((short*)C2)[((size_t)(bb * 16 + hh) * 128 + (c - 128)) * 2048 + t2] = pk;
        }
      } else if (MODE == 3) {
        int bb = m_ >> 11, t2 = m_ & 2047;
        if (n < 3072) {
          int hh = n / 192, c = n % 192;
          size_t rowb = (size_t)(bb * 16 + hh) * 2048 + t2;
          if (c < 128) {
#pragma unroll
            for (int r = 0; r < 4; r++)
              ((short*)C1)[(rowb + r) * 192 + c] = f2bf(acc[i][j][r] * 0.10411756f);
          } else {
#pragma unroll
            for (int r = 0; r < 4; r++)
              ((short*)C2)[(rowb + r) * 64 + (c - 128)] = f2bf(acc[i][j][r]);
          }
        } else if (n < 3584) {
          int c2 = n - 3072;
#pragma unroll
          for (int r = 0; r < 4; r++)
            ((short*)C3)[(size_t)(bb * 2048 + t2 + r) * 512 + c2] = f2bf(acc[i][j][r]);
        } else if (n < 3648) {
#pragma unroll
          for (int r = 0; r < 4; r++)
            ((short*)C4)[(size_t)(bb * 2048 + t2 + r) * 64 + (n - 3584)] = f2bf(acc[i][j][r]);
        }
      } else {
#pragma unroll
        for (int r = 0; r < 4; r++) {
          float v = acc[i][j][r];
          if (MODE == 0)
            ((short*)C1)[(size_t)(m_ + r) * N + n] = f2bf(v);
          else
            ((float*)C1)[(size_t)(m_ + r) * N + n] = v;
        }
      }
    }
  }
}

// ---------------- merged prep: rmsnorm + q-rope + k-rope in one launch ----------------
__global__ __launch_bounds__(256) void prep_k(const short* __restrict__ kvraw,
                                              const float* __restrict__ kvw,
                                              short* __restrict__ kvlat,
                                              const short* __restrict__ qrs,
                                              const short* __restrict__ krs,
                                              const float* __restrict__ freq,
                                              short* __restrict__ q_all,
                                              short* __restrict__ k_all) {
  int id = blockIdx.x;
  if (id < 1024) {
    int row = id * 4 + (threadIdx.x >> 6);
    int lane = threadIdx.x & 63;
    bf16x8 v = *(const bf16x8*)(kvraw + (size_t)row * 512 + lane * 8);
    float f[8];
    float ss = 0.f;
#pragma unroll
    for (int j = 0; j < 8; j++) { f[j] = bf2f(v[j]); ss += f[j] * f[j]; }
#pragma unroll
    for (int m = 1; m < 64; m <<= 1) ss += __shfl_xor(ss, m);
    float r = rsqrtf(ss * (1.f / 512.f) + 1e-6f);
    bf16x8 o;
#pragma unroll
    for (int j = 0; j < 8; j++) o[j] = f2bf(f[j] * r * kvw[lane * 8 + j]);
    *(bf16x8*)(kvlat + (size_t)row * 512 + lane * 8) = o;
  } else if (id < 3072) {
    int g = (id - 1024) * 256 + threadIdx.x;
    int row = g >> 3, p = g & 7;
    int t = row & 2047;
    const float scale = 0.10411756f;  // log2(e)/sqrt(192)
    bf16x8 v = *(const bf16x8*)(qrs + (size_t)row * 64 + p * 8);
    float4 fa = *(const float4*)(freq + t * 64 + p * 8);
    float4 fb = *(const float4*)(freq + t * 64 + p * 8 + 4);
    float cs[8] = {fa.x, fa.y, fa.z, fa.w, fb.x, fb.y, fb.z, fb.w};
    bf16x8 o;
#pragma unroll
    for (int j = 0; j < 4; j++) {
      float c = cs[2 * j], s = cs[2 * j + 1];
      float x0 = bf2f(v[2 * j]), x1 = bf2f(v[2 * j + 1]);
      o[2 * j] = f2bf((x0 * c - x1 * s) * scale);
      o[2 * j + 1] = f2bf((x1 * c + x0 * s) * scale);
    }
    *(bf16x8*)(q_all + (size_t)row * 192 + 128 + p * 8) = o;
  } else {
    int bt = (id - 3072) * 4 + (threadIdx.x >> 6);
    int lane = threadIdx.x & 63;
    int b = bt >> 11, t = bt & 2047;
    int p = lane >> 1;
    float c = freq[t * 64 + p * 2], s = freq[t * 64 + p * 2 + 1];
    float x0 = bf2f(krs[(size_t)bt * 64 + 2 * p]);
    float x1 = bf2f(krs[(size_t)bt * 64 + 2 * p + 1]);
    float v = (lane & 1) ? (x1 * c + x0 * s) : (x0 * c - x1 * s);
    short vb = f2bf(v);
#pragma unroll
    for (int h = 0; h < 16; h++)
      k_all[((size_t)(b * 16 + h) * 2048 + t) * 192 + 128 + lane] = vb;
  }
}

// ---------------- flash attention v10 (R13/R15/R18/R20-proven, ~84us) ----------------
__device__ __forceinline__ void stage6(const short* __restrict__ Kp,
                                       const short* __restrict__ VT,
                                       short* kb, short* vb, int kt, int ptid) {
#pragma unroll
  for (int c = 0; c < 6; c++) {
    int idx = c * 256 + ptid;          // boundary 832 = 13*64 -> wave-uniform branch
    if (idx < 832) {
      int r = idx / 25; if (r > 31) r = 31;
      int s = idx % 25;
      int s2 = (s >= 24) ? 0 : s;      // per-lane ADDRESS clamp, not divergence
      gl16(Kp + (size_t)(kt + r) * 192 + s2 * 8, kb + idx * 8);
    } else {
      int v = idx - 832;
      int r = v / 5; if (r > 127) r = 127;
      int s = v % 5;
      int s2 = (s >= 4) ? 0 : s;
      gl16(VT + (size_t)r * 2048 + kt + s2 * 8, vb + v * 8);
    }
  }
}

__global__ __launch_bounds__(512, 2) void attn_k(const short* __restrict__ q_all,
                                                 const short* __restrict__ k_all,
                                                 const short* __restrict__ vt,
                                                 short* __restrict__ attn_out) {
  __shared__ short kbuf[3][832 * 8];   // 3 x 13,312 B
  __shared__ short vbuf[3][704 * 8];   // 3 x 11,264 B   (total 73,728 B; 2 blocks/CU)
  int bh = blockIdx.x;
  int b = bh >> 4, h = bh & 15;
  int col = gridDim.y - 1 - blockIdx.y;  // longest first (LPT)
  int tid = threadIdx.x;
  int wave = tid >> 6, lane = tid & 63;
  int l31 = lane & 31, hi = lane >> 5;
  const bool producer = (wave >= 4);
  int qw = col * 128 + (wave & 3) * 32;  // consumer meaning
  int qrow = qw + l31;
  const short* Q = q_all + ((size_t)bh * 2048 + qrow) * 192;
  const short* Kp = k_all + (size_t)bh * 2048 * 192;
  const short* VT = vt + (size_t)bh * 128 * 2048;
  // sigma(l31): swap bits 2 and 3 (aligns S^T D-frag regs with PV B-operand k-order)
  int sig = (l31 & 19) | ((l31 >> 1) & 4) | ((l31 << 1) & 8);

  bf16x8 qf[12];
  f32x16 o[4];
  f32x16 sInit, zro;
#pragma unroll
  for (int r = 0; r < 16; r++) { sInit[r] = -28.8539f; zro[r] = 0.f; }  // -20*log2(e)
  float lsum = 0.f;
  if (!producer) {
#pragma unroll
    for (int kb = 0; kb < 12; kb++)
      qf[kb] = *(const bf16x8*)(Q + kb * 16 + hi * 8);
#pragma unroll
    for (int vb = 0; vb < 4; vb++)
#pragma unroll
      for (int r = 0; r < 16; r++) o[vb][r] = 0.f;
  }

  const int nt = (col * 128 + 128) >> 5;

  if (producer) {
    stage6(Kp, VT, kbuf[0], vbuf[0], 0, tid - 256);
    if (nt > 1) stage6(Kp, VT, kbuf[1], vbuf[1], 32, tid - 256);
    asm volatile("s_waitcnt vmcnt(6)" ::: "memory");  // buf0 complete; buf1 in flight
  }
  HWBAR();

  for (int t = 0; t < nt; t++) {
    if (producer) {
      if (t + 2 < nt) {
        stage6(Kp, VT, kbuf[(t + 2) % 3], vbuf[(t + 2) % 3], (t + 2) << 5, tid - 256);
        asm volatile("s_waitcnt vmcnt(6)" ::: "memory");  // buf[t+1] complete
      } else {
        asm volatile("s_waitcnt vmcnt(0)" ::: "memory");
      }
    } else {
      int kt = t << 5;
      int cur = t % 3;
      if (kt < qw + 32) {
        // ---- QK^T (swapped): S^T[key][q], two independent 6-chains ----
        f32x16 sc = sInit, sc2 = zro;
        __builtin_amdgcn_s_setprio(1);
#pragma unroll
        for (int kb = 0; kb < 6; kb++) {
          int c0 = 2 * kb + hi, c1 = 2 * (kb + 6) + hi;
          bf16x8 kf0 = *(const bf16x8*)&kbuf[cur][sig * 200 + (c0 << 3)];
          bf16x8 kf1 = *(const bf16x8*)&kbuf[cur][sig * 200 + (c1 << 3)];
          sc = MFMA32(kf0, qf[kb], sc);
          sc2 = MFMA32(kf1, qf[kb + 6], sc2);
        }
        __builtin_amdgcn_s_setprio(0);
#pragma unroll
        for (int r = 0; r < 16; r++) sc[r] += sc2[r];
        // ---- softmax (lane-local), pack to bf16 pairs ----
        unsigned pw[8];
        if (kt + 32 <= qw) {  // fully unmasked tile
#pragma unroll
          for (int r2 = 0; r2 < 8; r2++) {
            float pa = exp2f(sc[2 * r2]);
            float pb = exp2f(sc[2 * r2 + 1]);
            lsum += pa + pb;
            pw[r2] = cvtpk(pa, pb);
          }
        } else {
#pragma unroll
          for (int r2 = 0; r2 < 8; r2++) {
            int r = 2 * r2;
            int key = kt + (r & 3) + 4 * ((r >> 2) & 1) + 8 * hi + 16 * (r >> 3);
            float va = (key <= qrow) ? sc[r] : -1e30f;
            float vb2 = (key + 1 <= qrow) ? sc[r + 1] : -1e30f;
            float pa = exp2f(va);
            float pb = exp2f(vb2);
            lsum += pa + pb;
            pw[r2] = cvtpk(pa, pb);
          }
        }
        union { unsigned u[4]; bf16x8 v; } p0, p1;
#pragma unroll
        for (int w = 0; w < 4; w++) { p0.u[w] = pw[w]; p1.u[w] = pw[4 + w]; }
        // ---- PV (swapped): O^T[v][q] ----
        __builtin_amdgcn_s_setprio(1);
#pragma unroll
        for (int vb = 0; vb < 4; vb++) {
          int vcol = vb * 32 + l31;
          bf16x8 vf0 = *(const bf16x8*)&vbuf[cur][vcol * 40 + (hi << 3)];
          bf16x8 vf1 = *(const bf16x8*)&vbuf[cur][vcol * 40 + ((2 + hi) << 3)];
          o[vb] = MFMA32(vf0, p0.v, o[vb]);
          o[vb] = MFMA32(vf1, p1.v, o[vb]);
        }
        __builtin_amdgcn_s_setprio(0);
      }
    }
    HWBAR();
  }

  if (!producer) {
    lsum += __shfl_xor(lsum, 32);
    float inv = 1.f / lsum;
    size_t base = ((size_t)b * 2048 + qrow) * 2048 + h * 128;
#pragma unroll
    for (int vb = 0; vb < 4; vb++) {
#pragma unroll
      for (int r2 = 0; r2 < 8; r2++) {
        int r = 2 * r2;
        int v = vb * 32 + (r & 3) + 8 * (r >> 2) + 4 * hi;
        unsigned pk2 = ((unsigned)(unsigned short)f2bf(o[vb][r] * inv)) |
                       (((unsigned)(unsigned short)f2bf(o[vb][r + 1] * inv)) << 16);
        *(unsigned*)(attn_out + base + v) = pk2;
      }
    }
  }
}

extern "C" void kernel_launch(void* const* d_in, const int* in_sizes, int n_in,
                              void* d_out, int out_size, void* d_ws, size_t ws_size,
                              hipStream_t stream) {
  const float* x = (const float*)d_in[0];
  const float* freq = (const float*)d_in[1];
  const float* Wq = (const float*)d_in[4];
  const float* Wckv = (const float*)d_in[5];
  const float* kvw = (const float*)d_in[6];
  const float* Wdkv = (const float*)d_in[7];
  const float* Wproj = (const float*)d_in[8];

  char* ws = (char*)d_ws;
  size_t off = 0;
  auto alloc = [&](size_t bytes) {
    size_t o = off;
    off += (bytes + 255) & ~(size_t)255;
    return o;
  };
  size_t o_xbf = alloc(4096ull * 2048 * 2);
  size_t o_wqc = alloc(3840ull * 2048 * 2);
  size_t o_wdkv = alloc(4096ull * 512 * 2);
  size_t o_wproj = alloc(2048ull * 2048 * 2);
  size_t o_qrs = alloc(32ull * 2048 * 64 * 2);
  size_t o_kvraw = alloc(4096ull * 512 * 2);
  size_t o_krs = alloc(4096ull * 64 * 2);
  size_t o_kvlat = alloc(4096ull * 512 * 2);
  size_t o_qall = alloc(32ull * 2048 * 192 * 2);
  size_t o_kall = alloc(32ull * 2048 * 192 * 2);
  size_t o_vt = alloc(32ull * 128 * 2048 * 2);
  size_t o_attn = o_xbf;  // alias: x_bf dead after GEMM1

  short* x_bf = (short*)(ws + o_xbf);
  short* wqc = (short*)(ws + o_wqc);
  short* wdkv = (short*)(ws + o_wdkv);
  short* wproj = (short*)(ws + o_wproj);
  short* qrs = (short*)(ws + o_qrs);
  short* kvraw = (short*)(ws + o_kvraw);
  short* krs = (short*)(ws + o_krs);
  short* kvlat = (short*)(ws + o_kvlat);
  short* qall = (short*)(ws + o_qall);
  short* kall = (short*)(ws + o_kall);
  short* vtb = (short*)(ws + o_vt);
  short* attnb = (short*)(ws + o_attn);

  wcvt2_k<<<17920, 256, 0, stream>>>(x, Wq, Wckv, Wdkv, Wproj, x_bf, wqc, wdkv, wproj);

  gemm8_k<3, 256, 256, 4><<<240, 512, 0, stream>>>(x_bf, wqc, qall, qrs, kvraw, krs,
                                                   4096, 3712, 2048, 16);

  prep_k<<<4096, 256, 0, stream>>>(kvraw, kvw, kvlat, qrs, krs, freq, qall, kall);

  gemm8_k<2, 256, 256, 4><<<256, 512, 0, stream>>>(kvlat, wdkv, kall, vtb, nullptr, nullptr,
                                                   4096, 4096, 512, 16);

  attn_k<<<dim3(32, 16), 512, 0, stream>>>(qall, kall, vtb, attnb);

  gemm8_k<1, 128, 256, 3><<<256, 512, 0, stream>>>(attnb, wproj, d_out, nullptr, nullptr, nullptr,
                                                   4096, 2048, 2048, 32);
}